// Round 1
// 1499.302 us; speedup vs baseline: 1.3048x; 1.3048x over previous
//
#include <hip/hip_runtime.h>

// ---------------------------------------------------------------- constants
namespace {
constexpr int   B_   = 16;
constexpr int   N_   = 20000;
constexpr int   C_   = 64;
constexpr int   DIM_ = 128;
constexpr int   E_   = 640000;
constexpr int   NB_  = 3;
constexpr int   ROW_ = B_ * C_;      // 1024 elements per node row in [N,B,C]
constexpr int   NR_  = N_ * B_;      // 320000 rows of C elements

constexpr int   LDP  = 200;          // LDS row stride (shorts): 400B = 100 dwords,
                                     // 100 % 32 = 4 -> 2-way max on b128 reads (free)

// SpMM phase blocking
constexpr int   PH_   = 16;          // phases
constexpr int   PCOL_ = ROW_ / PH_;  // 64 cols (128B) per phase
constexpr int   NPB_  = 16;          // nodes per block (16 lanes each)
constexpr int   NCHK_ = N_ / NPB_;   // 1250 chunks per phase
constexpr int   NBIN_ = 1024;        // degree-sort bins

// bf16 weight region sizes (elements)
constexpr int   SZ1_ = 128 * 192;    // Wc^T  per block
constexpr int   SZ2_ = 128 * 128;    // w1^T  per block
constexpr int   SZ3_ = 64 * 128;     // w2^T  per block
constexpr int   SZB_ = SZ1_ + SZ2_ + SZ3_;
constexpr int   WTOT_ = NB_ * SZB_;

// workspace layout (bytes)
constexpr size_t SZH_  = (size_t)N_ * ROW_ * sizeof(float);   // fp32 h
constexpr size_t SZHB_ = (size_t)N_ * ROW_ * 2;               // bf16 row image
constexpr size_t OFF_H    = 0;
constexpr size_t OFF_HB   = SZH_;
constexpr size_t OFF_T1B  = OFF_HB  + SZHB_;
constexpr size_t OFF_SB   = OFF_T1B + SZHB_;
constexpr size_t OFF_DEG  = OFF_SB  + SZHB_;
constexpr size_t OFF_CNT  = OFF_DEG + (size_t)N_ * 4;
constexpr size_t OFF_OFFS = OFF_CNT + (size_t)N_ * 4;
constexpr size_t OFF_CV   = ((OFF_OFFS + (size_t)(N_ + 1) * 4 + 255) / 256) * 256;
constexpr size_t OFF_PERM = OFF_CV   + (size_t)E_ * 8;
constexpr size_t OFF_HIST = OFF_PERM + (size_t)N_ * 4;
constexpr size_t OFF_HOFF = OFF_HIST + (size_t)NBIN_ * 4;
constexpr size_t OFF_HFIL = OFF_HOFF + (size_t)NBIN_ * 4;
constexpr size_t OFF_WTC  = OFF_HFIL + (size_t)NBIN_ * 4;
constexpr size_t OFF_WT1  = OFF_WTC + (size_t)NB_ * SZ1_ * 2;
constexpr size_t OFF_WT2  = OFF_WT1 + (size_t)NB_ * SZ2_ * 2;
// total ~210 MB
} // namespace

typedef short s16x8 __attribute__((ext_vector_type(8)));
typedef float f32x4 __attribute__((ext_vector_type(4)));
typedef unsigned int u32;

__device__ __forceinline__ u32 bfr(float x) {
    u32 u = __float_as_uint(x);
    return (u + 0x7FFFu + ((u >> 16) & 1u)) >> 16;
}
__device__ __forceinline__ u32 pack_bf2(float x, float y) {
    return bfr(x) | (bfr(y) << 16);
}
__device__ __forceinline__ float bflo(u32 u) { return __uint_as_float(u << 16); }
__device__ __forceinline__ float bfhi(u32 u) { return __uint_as_float(u & 0xFFFF0000u); }

// ---------------------------------------------------------------- graph prep
__global__ void deg_cnt_k(const int* __restrict__ src, const int* __restrict__ dst,
                          const float* __restrict__ ew,
                          float* __restrict__ deg, int* __restrict__ cnt) {
    int e = blockIdx.x * 256 + threadIdx.x;
    if (e < E_) {
        atomicAdd(deg + src[e], ew[e]);
        atomicAdd(cnt + dst[e], 1);
    }
}

__global__ void dinv_k(float* __restrict__ deg) {
    int i = blockIdx.x * 256 + threadIdx.x;
    if (i < N_) {
        float d = deg[i];
        deg[i] = (d > 0.f) ? rsqrtf(fmaxf(d, 1e-12f)) : 0.f;
    }
}

__global__ __launch_bounds__(1024) void scan_k(const int* __restrict__ cnt,
                                               int* __restrict__ offs) {
    __shared__ int sums[1024];
    const int tid = threadIdx.x;
    constexpr int CH = (N_ + 1023) / 1024;   // 20
    const int base = tid * CH;
    int local = 0;
    for (int j = 0; j < CH; ++j) {
        int i = base + j;
        if (i < N_) local += cnt[i];
    }
    sums[tid] = local;
    __syncthreads();
    for (int off = 1; off < 1024; off <<= 1) {
        int v = sums[tid];
        int u = (tid >= off) ? sums[tid - off] : 0;
        __syncthreads();
        sums[tid] = v + u;
        __syncthreads();
    }
    int run = (tid > 0) ? sums[tid - 1] : 0;
    for (int j = 0; j < CH; ++j) {
        int i = base + j;
        if (i < N_) { offs[i] = run; run += cnt[i]; }
    }
    if (tid == 1023) offs[N_] = sums[1023];
}

// degree histogram / scan / perm-scatter (degree-sorted node order)
__global__ void hist_k(const int* __restrict__ cnt, int* __restrict__ hist) {
    int i = blockIdx.x * 256 + threadIdx.x;
    if (i < N_) atomicAdd(hist + min(cnt[i], NBIN_ - 1), 1);
}

__global__ __launch_bounds__(1024) void hscan_k(const int* __restrict__ hist,
                                                int* __restrict__ hoffs) {
    __shared__ int s[NBIN_];
    int t = threadIdx.x;
    s[t] = hist[t];
    __syncthreads();
    for (int off = 1; off < NBIN_; off <<= 1) {
        int v = s[t];
        int u = (t >= off) ? s[t - off] : 0;
        __syncthreads();
        s[t] = v + u;
        __syncthreads();
    }
    hoffs[t] = (t > 0) ? s[t - 1] : 0;
}

__global__ void permscatter_k(const int* __restrict__ cnt, const int* __restrict__ hoffs,
                              int* __restrict__ hfill, int* __restrict__ perm) {
    int i = blockIdx.x * 256 + threadIdx.x;
    if (i < N_) {
        int b = min(cnt[i], NBIN_ - 1);
        int pos = hoffs[b] + atomicAdd(hfill + b, 1);
        perm[pos] = i;
    }
}

__global__ void scatter_k(const int* __restrict__ src, const int* __restrict__ dst,
                          const float* __restrict__ ew, const float* __restrict__ dinv,
                          const int* __restrict__ offs, int* __restrict__ fill,
                          int2* __restrict__ cv) {
    int e = blockIdx.x * 256 + threadIdx.x;
    if (e < E_) {
        int s = src[e], d = dst[e];
        int pos = offs[d] + atomicAdd(fill + d, 1);
        float w = -dinv[s] * ew[e] * dinv[d];
        cv[pos] = make_int2(s, __float_as_int(w));
    }
}

// ---------------------------------------------------------------- bf16 weight prep
__global__ void wprep_k(const float* __restrict__ cw, const float* __restrict__ w1,
                        const float* __restrict__ w2,
                        short* __restrict__ wtc, short* __restrict__ wt1,
                        short* __restrict__ wt2) {
    int idx = blockIdx.x * 256 + threadIdx.x;
    if (idx >= WTOT_) return;
    int b = idx / SZB_;
    int rem = idx - b * SZB_;
    if (rem < SZ1_) {
        int n = rem / 192, k = rem - n * 192;
        int part = k >> 6, c = k & 63;
        const float* base = cw + (size_t)b * 3 * 64 * 128;
        float v;
        if (part == 0)      v = base[c * 128 + n] - base[16384 + c * 128 + n];
        else if (part == 1) v = base[8192 + c * 128 + n];
        else                v = 2.f * base[16384 + c * 128 + n];
        wtc[(size_t)b * SZ1_ + n * 192 + k] = (short)bfr(v);
    } else if (rem < SZ1_ + SZ2_) {
        int r2 = rem - SZ1_;
        int n = r2 >> 7, k = r2 & 127;
        float v = w1[(size_t)b * 16384 + k * 128 + n];
        wt1[(size_t)b * SZ2_ + n * 128 + k] = (short)bfr(v);
    } else {
        int r3 = rem - SZ1_ - SZ2_;
        int n = r3 >> 7, k = r3 & 127;
        float v = w2[(size_t)b * 8192 + k * 64 + n];
        wt2[(size_t)b * SZ3_ + n * 128 + k] = (short)bfr(v);
    }
}

// ---------------------------------------------------------------- transposes
__global__ void transpose_in_k(const float* __restrict__ x, float* __restrict__ h,
                               ushort* __restrict__ hb) {
    int idx = blockIdx.x * 256 + threadIdx.x;
    int c4 = idx & 15;
    int nb = idx >> 4;        // n*B + b
    int b  = nb & (B_ - 1);
    int n  = nb >> 4;
    const float4 v = *(const float4*)(x + ((size_t)b * N_ + n) * C_ + (c4 << 2));
    *(float4*)(h + (size_t)nb * C_ + (c4 << 2)) = v;
    uint2 p;
    p.x = pack_bf2(v.x, v.y);
    p.y = pack_bf2(v.z, v.w);
    *(uint2*)(hb + (size_t)nb * C_ + (c4 << 2)) = p;
}

__global__ void transpose_out_k(const float* __restrict__ h, float* __restrict__ out) {
    int idx = blockIdx.x * 256 + threadIdx.x;
    int c4 = idx & 15;
    int nb = idx >> 4;
    int b  = nb & (B_ - 1);
    int n  = nb >> 4;
    const float4 v = *(const float4*)(h + (size_t)nb * C_ + (c4 << 2));
    *(float4*)(out + ((size_t)b * N_ + n) * C_ + (c4 << 2)) = v;
}

// ---------------------------------------------------------------- SpMM, phase-blocked
// grid = PH_*NCHK_ blocks (phase-major). Block: 16 nodes x 16 lanes; lane owns 8B
// of the node's 128B phase-slice. Per phase the gather working set is N*128B =
// 2.56 MB -> XCD-L2 resident. Nodes processed in degree-sorted order (perm).
__global__ __launch_bounds__(256) void spmm_ph_k(const ushort* __restrict__ in,
                                                 ushort* __restrict__ out,
                                                 const int* __restrict__ offs,
                                                 const int2* __restrict__ cv,
                                                 const int* __restrict__ perm) {
    const int blk = blockIdx.x;
    const int ph  = blk / NCHK_;
    const int chunk = blk - ph * NCHK_;
    const int g      = threadIdx.x >> 4;
    const int lane16 = threadIdx.x & 15;
    const int n = perm[chunk * NPB_ + g];
    const int s0 = offs[n], s1 = offs[n + 1];
    const size_t coff = (size_t)ph * PCOL_ + (lane16 << 2);

    float a0 = 0.f, a1 = 0.f, a2 = 0.f, a3 = 0.f;
    int i = s0;
    for (; i + 3 < s1; i += 4) {
        int2 e0 = cv[i], e1 = cv[i + 1], e2 = cv[i + 2], e3 = cv[i + 3];
        uint2 v0 = *(const uint2*)(in + (size_t)e0.x * ROW_ + coff);
        uint2 v1 = *(const uint2*)(in + (size_t)e1.x * ROW_ + coff);
        uint2 v2 = *(const uint2*)(in + (size_t)e2.x * ROW_ + coff);
        uint2 v3 = *(const uint2*)(in + (size_t)e3.x * ROW_ + coff);
        float w0 = __int_as_float(e0.y), w1 = __int_as_float(e1.y);
        float w2 = __int_as_float(e2.y), w3 = __int_as_float(e3.y);
        a0 += w0 * bflo(v0.x) + w1 * bflo(v1.x) + w2 * bflo(v2.x) + w3 * bflo(v3.x);
        a1 += w0 * bfhi(v0.x) + w1 * bfhi(v1.x) + w2 * bfhi(v2.x) + w3 * bfhi(v3.x);
        a2 += w0 * bflo(v0.y) + w1 * bflo(v1.y) + w2 * bflo(v2.y) + w3 * bflo(v3.y);
        a3 += w0 * bfhi(v0.y) + w1 * bfhi(v1.y) + w2 * bfhi(v2.y) + w3 * bfhi(v3.y);
    }
    for (; i < s1; ++i) {
        int2 e0 = cv[i];
        uint2 v0 = *(const uint2*)(in + (size_t)e0.x * ROW_ + coff);
        float w0 = __int_as_float(e0.y);
        a0 += w0 * bflo(v0.x);
        a1 += w0 * bfhi(v0.x);
        a2 += w0 * bflo(v0.y);
        a3 += w0 * bfhi(v0.y);
    }
    uint2 p;
    p.x = pack_bf2(a0, a1);
    p.y = pack_bf2(a2, a3);
    *(uint2*)(out + (size_t)n * ROW_ + coff) = p;
}

// ---------------------------------------------------------------- MFMA MLP block
// Re-partitioned (r6): each of the 4 waves owns a COLUMN SLICE (32/128 cols for
// stages 1-2, 16/64 for stage 3) across ALL 64 rows of the block. Weight
// fragments per wave drop 4x (96 -> 24) and are held in explicit register
// arrays (forces batched issue; the old structure had VGPR_Count=56 and
// serialized every L2 weight load -> 264us latency-bound). A-tile [64x192] =
// [hb|t1b|sb] is reg-staged into LDS once per block; g1/g2 alias the same LDS
// buffer between barriers. LDS row stride 200 shorts (400B = 100 dwords, ≡4
// banks/row) -> only free 2-way conflicts on ds_read_b128. LDS 25600B.
__global__ __launch_bounds__(256, 4) void mlp_mfma_k(
        float* __restrict__ h, ushort* __restrict__ hb,
        const ushort* __restrict__ t1b, const ushort* __restrict__ sb,
        const short* __restrict__ wtc, const short* __restrict__ wt1,
        const short* __restrict__ wt2,
        const float* __restrict__ cbias, const float* __restrict__ b1,
        const float* __restrict__ b2, const float* __restrict__ betap) {
    __shared__ __align__(16) short u[64 * LDP];

    const int tid  = threadIdx.x;
    const int wv   = tid >> 6;
    const int lane = tid & 63;
    const int m    = lane & 15;
    const int q    = lane >> 4;
    const int row0 = blockIdx.x * 64;
    const float sp    = __logf(1.f + __expf(betap[0]));
    const float inv11 = 1.0f / 1.1f;

    // ---- stage-1 weight fragments (12): cols n = wv*32 + t*16 + m, k = kb*32+q*8
    s16x8 wA[6][2];
#pragma unroll
    for (int kb = 0; kb < 6; ++kb)
#pragma unroll
        for (int t = 0; t < 2; ++t)
            wA[kb][t] = *(const s16x8*)(wtc + ((wv << 5) + (t << 4) + m) * 192
                                            + (kb << 5) + (q << 3));

    // ---- cooperative A-tile fill: [64 rows][192 cols] = [hb|t1b|sb], batched
    {
        const ushort* srcs[3] = { hb, t1b, sb };
        s16x8 tv[3][2];
#pragma unroll
        for (int s = 0; s < 3; ++s)
#pragma unroll
            for (int i = 0; i < 2; ++i) {
                int ck = tid + (i << 8);            // 0..511
                int r = ck >> 3, c8 = ck & 7;
                tv[s][i] = *(const s16x8*)(srcs[s] + (size_t)(row0 + r) * C_ + (c8 << 3));
            }
#pragma unroll
        for (int s = 0; s < 3; ++s)
#pragma unroll
            for (int i = 0; i < 2; ++i) {
                int ck = tid + (i << 8);
                int r = ck >> 3, c8 = ck & 7;
                *(s16x8*)(u + r * LDP + (s << 6) + (c8 << 3)) = tv[s][i];
            }
    }
    __syncthreads();

    // ---- stage 1: A(64x192) @ Wc^T-slice -> acc[rg][t] (64 rows x 32 cols/wave)
    f32x4 acc[4][2];
#pragma unroll
    for (int rg = 0; rg < 4; ++rg)
#pragma unroll
        for (int t = 0; t < 2; ++t) acc[rg][t] = (f32x4){0.f, 0.f, 0.f, 0.f};
#pragma unroll
    for (int kb = 0; kb < 6; ++kb)
#pragma unroll
        for (int rg = 0; rg < 4; ++rg) {
            s16x8 af = *(const s16x8*)(u + ((rg << 4) + m) * LDP + (kb << 5) + (q << 3));
            acc[rg][0] = __builtin_amdgcn_mfma_f32_16x16x32_bf16(af, wA[kb][0], acc[rg][0], 0, 0, 0);
            acc[rg][1] = __builtin_amdgcn_mfma_f32_16x16x32_bf16(af, wA[kb][1], acc[rg][1], 0, 0, 0);
        }
    __syncthreads();   // all waves done reading A-tile; u now becomes g1

    // stage-2 weight prefetch (overlaps epilogue-1 VALU; wA is dead now)
    s16x8 wB[4][2];
#pragma unroll
    for (int k4 = 0; k4 < 4; ++k4)
#pragma unroll
        for (int t = 0; t < 2; ++t)
            wB[k4][t] = *(const s16x8*)(wt1 + (((wv << 5) + (t << 4) + m) << 7)
                                            + (k4 << 5) + (q << 3));

    // ---- epilogue 1: bias + swish -> g1 (cols wv*32..wv*32+31, all 64 rows)
    {
        float cb0 = cbias[(wv << 5) + m];
        float cb1 = cbias[(wv << 5) + 16 + m];
#pragma unroll
        for (int rg = 0; rg < 4; ++rg)
#pragma unroll
            for (int t = 0; t < 2; ++t) {
                float bv = t ? cb1 : cb0;
#pragma unroll
                for (int r = 0; r < 4; ++r) {
                    float o = acc[rg][t][r] + bv;
                    float g = o * (1.f / (1.f + __expf(-o * sp))) * inv11;
                    u[((rg << 4) + (q << 2) + r) * LDP + (wv << 5) + (t << 4) + m] =
                        (short)bfr(g);
                }
            }
    }
    __syncthreads();

    // ---- stage 2: g1(64x128) @ w1^T-slice
    f32x4 acc2[4][2];
#pragma unroll
    for (int rg = 0; rg < 4; ++rg)
#pragma unroll
        for (int t = 0; t < 2; ++t) acc2[rg][t] = (f32x4){0.f, 0.f, 0.f, 0.f};
#pragma unroll
    for (int k4 = 0; k4 < 4; ++k4)
#pragma unroll
        for (int rg = 0; rg < 4; ++rg) {
            s16x8 af = *(const s16x8*)(u + ((rg << 4) + m) * LDP + (k4 << 5) + (q << 3));
            acc2[rg][0] = __builtin_amdgcn_mfma_f32_16x16x32_bf16(af, wB[k4][0], acc2[rg][0], 0, 0, 0);
            acc2[rg][1] = __builtin_amdgcn_mfma_f32_16x16x32_bf16(af, wB[k4][1], acc2[rg][1], 0, 0, 0);
        }
    __syncthreads();   // all waves done reading g1; u now becomes g2

    // stage-3 weight prefetch (overlaps epilogue-2 VALU)
    s16x8 wC[4];
#pragma unroll
    for (int k4 = 0; k4 < 4; ++k4)
        wC[k4] = *(const s16x8*)(wt2 + (((wv << 4) + m) << 7) + (k4 << 5) + (q << 3));

    // ---- epilogue 2: bias + swish -> g2
    {
        float b10 = b1[(wv << 5) + m];
        float b11 = b1[(wv << 5) + 16 + m];
#pragma unroll
        for (int rg = 0; rg < 4; ++rg)
#pragma unroll
            for (int t = 0; t < 2; ++t) {
                float bv = t ? b11 : b10;
#pragma unroll
                for (int r = 0; r < 4; ++r) {
                    float o = acc2[rg][t][r] + bv;
                    float g = o * (1.f / (1.f + __expf(-o * sp))) * inv11;
                    u[((rg << 4) + (q << 2) + r) * LDP + (wv << 5) + (t << 4) + m] =
                        (short)bfr(g);
                }
            }
    }
    __syncthreads();

    // ---- stage 3: g2(64x128) @ w2^T-slice -> 16 cols/wave
    f32x4 acc3[4];
#pragma unroll
    for (int rg = 0; rg < 4; ++rg) acc3[rg] = (f32x4){0.f, 0.f, 0.f, 0.f};
#pragma unroll
    for (int k4 = 0; k4 < 4; ++k4)
#pragma unroll
        for (int rg = 0; rg < 4; ++rg) {
            s16x8 af = *(const s16x8*)(u + ((rg << 4) + m) * LDP + (k4 << 5) + (q << 3));
            acc3[rg] = __builtin_amdgcn_mfma_f32_16x16x32_bf16(af, wC[k4], acc3[rg], 0, 0, 0);
        }

    // ---- epilogue 3: residual h += f (batched h loads), refresh hb
    {
        float b2v = b2[(wv << 4) + m];
        float hv[4][4];
#pragma unroll
        for (int rg = 0; rg < 4; ++rg)
#pragma unroll
            for (int r = 0; r < 4; ++r)
                hv[rg][r] = h[(size_t)(row0 + (rg << 4) + (q << 2) + r) * C_
                              + (wv << 4) + m];
#pragma unroll
        for (int rg = 0; rg < 4; ++rg)
#pragma unroll
            for (int r = 0; r < 4; ++r) {
                size_t eidx = (size_t)(row0 + (rg << 4) + (q << 2) + r) * C_
                              + (wv << 4) + m;
                float nv = hv[rg][r] + acc3[rg][r] + b2v;
                h[eidx]  = nv;
                hb[eidx] = (ushort)bfr(nv);
            }
    }
}

// ---------------------------------------------------------------- launch
extern "C" void kernel_launch(void* const* d_in, const int* in_sizes, int n_in,
                              void* d_out, int out_size, void* d_ws, size_t ws_size,
                              hipStream_t stream) {
    const float* x    = (const float*)d_in[0];
    const int*   ei   = (const int*)d_in[1];
    const float* ew   = (const float*)d_in[2];
    const float* cw   = (const float*)d_in[3];
    const float* cb   = (const float*)d_in[4];
    const float* beta = (const float*)d_in[5];
    const float* w1   = (const float*)d_in[6];
    const float* b1   = (const float*)d_in[7];
    const float* w2   = (const float*)d_in[8];
    const float* b2   = (const float*)d_in[9];
    float* out = (float*)d_out;

    char* ws = (char*)d_ws;
    float*  h_t  = (float*) (ws + OFF_H);
    ushort* hb   = (ushort*)(ws + OFF_HB);
    ushort* t1b  = (ushort*)(ws + OFF_T1B);
    ushort* sb   = (ushort*)(ws + OFF_SB);
    float*  deg  = (float*) (ws + OFF_DEG);
    int*    cnt  = (int*)   (ws + OFF_CNT);
    int*    offs = (int*)   (ws + OFF_OFFS);
    int2*   cv   = (int2*)  (ws + OFF_CV);
    int*    perm = (int*)   (ws + OFF_PERM);
    int*    hist = (int*)   (ws + OFF_HIST);
    int*    hoff = (int*)   (ws + OFF_HOFF);
    int*    hfil = (int*)   (ws + OFF_HFIL);
    short*  wtc  = (short*) (ws + OFF_WTC);
    short*  wt1  = (short*) (ws + OFF_WT1);
    short*  wt2  = (short*) (ws + OFF_WT2);

    const int* srcI = ei;
    const int* dstI = ei + E_;

    // graph prep
    hipMemsetAsync(deg, 0, (size_t)N_ * 4, stream);
    hipMemsetAsync(cnt, 0, (size_t)N_ * 4, stream);
    hipMemsetAsync(hist, 0, (size_t)NBIN_ * 4, stream);
    hipMemsetAsync(hfil, 0, (size_t)NBIN_ * 4, stream);
    deg_cnt_k<<<(E_ + 255) / 256, 256, 0, stream>>>(srcI, dstI, ew, deg, cnt);
    dinv_k<<<(N_ + 255) / 256, 256, 0, stream>>>(deg);
    scan_k<<<1, 1024, 0, stream>>>(cnt, offs);
    hist_k<<<(N_ + 255) / 256, 256, 0, stream>>>(cnt, hist);
    hscan_k<<<1, NBIN_, 0, stream>>>(hist, hoff);
    permscatter_k<<<(N_ + 255) / 256, 256, 0, stream>>>(cnt, hoff, hfil, perm);
    hipMemsetAsync(cnt, 0, (size_t)N_ * 4, stream);
    scatter_k<<<(E_ + 255) / 256, 256, 0, stream>>>(srcI, dstI, ew, deg, offs, cnt, cv);

    // bf16 weights
    wprep_k<<<(WTOT_ + 255) / 256, 256, 0, stream>>>(cw, w1, w2, wtc, wt1, wt2);

    // x -> [N,B,C] (fp32 + bf16 image)
    transpose_in_k<<<(N_ * B_ * 16) / 256, 256, 0, stream>>>(x, h_t, hb);

    for (int b = 0; b < NB_; ++b) {
        spmm_ph_k<<<PH_ * NCHK_, 256, 0, stream>>>(hb, t1b, offs, cv, perm);
        spmm_ph_k<<<PH_ * NCHK_, 256, 0, stream>>>(t1b, sb, offs, cv, perm);
        mlp_mfma_k<<<NR_ / 64, 256, 0, stream>>>(h_t, hb, t1b, sb,
                                                 wtc + (size_t)b * SZ1_,
                                                 wt1 + (size_t)b * SZ2_,
                                                 wt2 + (size_t)b * SZ3_,
                                                 cb + (size_t)b * DIM_,
                                                 b1 + (size_t)b * DIM_,
                                                 b2 + (size_t)b * C_,
                                                 beta + b);
    }

    // [N,B,C] -> out
    transpose_out_k<<<(N_ * B_ * 16) / 256, 256, 0, stream>>>(h_t, out);
}

// Round 2
// 1403.909 us; speedup vs baseline: 1.3934x; 1.0679x over previous
//
#include <hip/hip_runtime.h>

// ---------------------------------------------------------------- constants
namespace {
constexpr int   B_   = 16;
constexpr int   N_   = 20000;
constexpr int   C_   = 64;
constexpr int   DIM_ = 128;
constexpr int   E_   = 640000;
constexpr int   NB_  = 3;
constexpr int   ROW_ = B_ * C_;      // 1024 elements per node row in [N,B,C]
constexpr int   NR_  = N_ * B_;      // 320000 rows of C elements

constexpr int   LDP  = 200;          // LDS row stride (shorts): 400B = 100 dwords,
                                     // 100 % 32 = 4 -> 2-way max on b128 reads (free)

// SpMM phase blocking
constexpr int   PH_   = 16;          // phases
constexpr int   PCOL_ = ROW_ / PH_;  // 64 cols (128B) per phase
constexpr int   NPB_  = 16;          // nodes per block (16 lanes each)
constexpr int   NCHK_ = N_ / NPB_;   // 1250 chunks per phase
constexpr int   NBIN_ = 1024;        // degree-sort bins
constexpr int   NXCD_ = 8;           // XCDs; blockIdx % 8 -> XCD (round-robin)
constexpr int   EP_   = E_ + 3 * N_ + 64;   // padded edge capacity (lists %4)

// bf16 weight region sizes (elements)
constexpr int   SZ1_ = 128 * 192;    // Wc^T  per block
constexpr int   SZ2_ = 128 * 128;    // w1^T  per block
constexpr int   SZ3_ = 64 * 128;     // w2^T  per block
constexpr int   SZB_ = SZ1_ + SZ2_ + SZ3_;
constexpr int   WTOT_ = NB_ * SZB_;

// workspace layout (bytes)
constexpr size_t SZH_  = (size_t)N_ * ROW_ * sizeof(float);   // fp32 h
constexpr size_t SZHB_ = (size_t)N_ * ROW_ * 2;               // bf16 row image
constexpr size_t OFF_H    = 0;
constexpr size_t OFF_HB   = SZH_;
constexpr size_t OFF_T1B  = OFF_HB  + SZHB_;
constexpr size_t OFF_SB   = OFF_T1B + SZHB_;
constexpr size_t OFF_DEG  = OFF_SB  + SZHB_;
constexpr size_t OFF_CNT  = OFF_DEG + (size_t)N_ * 4;
constexpr size_t OFF_OFFS = OFF_CNT + (size_t)N_ * 4;
constexpr size_t OFF_CV   = ((OFF_OFFS + (size_t)(N_ + 1) * 4 + 255) / 256) * 256;
// esrc (u16[EP_]) + eww (f32[EP_]) live inside the old 8B-cv footprint
constexpr size_t OFF_ESRC = OFF_CV;
constexpr size_t OFF_EW   = ((OFF_ESRC + (size_t)EP_ * 2 + 255) / 256) * 256;
static_assert(OFF_EW + (size_t)EP_ * 4 <= OFF_CV + (size_t)E_ * 8, "cv region overflow");
constexpr size_t OFF_PERM = OFF_CV   + (size_t)E_ * 8;
constexpr size_t OFF_HIST = OFF_PERM + (size_t)N_ * 4;
constexpr size_t OFF_HOFF = OFF_HIST + (size_t)NBIN_ * 4;
constexpr size_t OFF_HFIL = OFF_HOFF + (size_t)NBIN_ * 4;
constexpr size_t OFF_WTC  = OFF_HFIL + (size_t)NBIN_ * 4;
constexpr size_t OFF_WT1  = OFF_WTC + (size_t)NB_ * SZ1_ * 2;
constexpr size_t OFF_WT2  = OFF_WT1 + (size_t)NB_ * SZ2_ * 2;
// total ~210 MB
} // namespace

typedef short s16x8 __attribute__((ext_vector_type(8)));
typedef float f32x4 __attribute__((ext_vector_type(4)));
typedef unsigned int u32;

__device__ __forceinline__ u32 bfr(float x) {
    u32 u = __float_as_uint(x);
    return (u + 0x7FFFu + ((u >> 16) & 1u)) >> 16;
}
__device__ __forceinline__ u32 pack_bf2(float x, float y) {
    return bfr(x) | (bfr(y) << 16);
}
__device__ __forceinline__ float bflo(u32 u) { return __uint_as_float(u << 16); }
__device__ __forceinline__ float bfhi(u32 u) { return __uint_as_float(u & 0xFFFF0000u); }

// ---------------------------------------------------------------- graph prep
__global__ void deg_cnt_k(const int* __restrict__ src, const int* __restrict__ dst,
                          const float* __restrict__ ew,
                          float* __restrict__ deg, int* __restrict__ cnt) {
    int e = blockIdx.x * 256 + threadIdx.x;
    if (e < E_) {
        atomicAdd(deg + src[e], ew[e]);
        atomicAdd(cnt + dst[e], 1);
    }
}

__global__ void dinv_k(float* __restrict__ deg) {
    int i = blockIdx.x * 256 + threadIdx.x;
    if (i < N_) {
        float d = deg[i];
        deg[i] = (d > 0.f) ? rsqrtf(fmaxf(d, 1e-12f)) : 0.f;
    }
}

// exclusive scan of per-node counts PADDED to multiples of 4 (branch-free spmm)
__global__ __launch_bounds__(1024) void scan_k(const int* __restrict__ cnt,
                                               int* __restrict__ offs) {
    __shared__ int sums[1024];
    const int tid = threadIdx.x;
    constexpr int CH = (N_ + 1023) / 1024;   // 20
    const int base = tid * CH;
    int local = 0;
    for (int j = 0; j < CH; ++j) {
        int i = base + j;
        if (i < N_) local += (cnt[i] + 3) & ~3;
    }
    sums[tid] = local;
    __syncthreads();
    for (int off = 1; off < 1024; off <<= 1) {
        int v = sums[tid];
        int u = (tid >= off) ? sums[tid - off] : 0;
        __syncthreads();
        sums[tid] = v + u;
        __syncthreads();
    }
    int run = (tid > 0) ? sums[tid - 1] : 0;
    for (int j = 0; j < CH; ++j) {
        int i = base + j;
        if (i < N_) { offs[i] = run; run += (cnt[i] + 3) & ~3; }
    }
    if (tid == 1023) offs[N_] = sums[1023];
}

// degree histogram / scan / perm-scatter (degree-sorted node order)
__global__ void hist_k(const int* __restrict__ cnt, int* __restrict__ hist) {
    int i = blockIdx.x * 256 + threadIdx.x;
    if (i < N_) atomicAdd(hist + min(cnt[i], NBIN_ - 1), 1);
}

__global__ __launch_bounds__(1024) void hscan_k(const int* __restrict__ hist,
                                                int* __restrict__ hoffs) {
    __shared__ int s[NBIN_];
    int t = threadIdx.x;
    s[t] = hist[t];
    __syncthreads();
    for (int off = 1; off < NBIN_; off <<= 1) {
        int v = s[t];
        int u = (t >= off) ? s[t - off] : 0;
        __syncthreads();
        s[t] = v + u;
        __syncthreads();
    }
    hoffs[t] = (t > 0) ? s[t - 1] : 0;
}

__global__ void permscatter_k(const int* __restrict__ cnt, const int* __restrict__ hoffs,
                              int* __restrict__ hfill, int* __restrict__ perm) {
    int i = blockIdx.x * 256 + threadIdx.x;
    if (i < N_) {
        int b = min(cnt[i], NBIN_ - 1);
        int pos = hoffs[b] + atomicAdd(hfill + b, 1);
        perm[pos] = i;
    }
}

// split edge store: u16 src + f32 weight (6B/edge, was 8B). pads stay 0 (memset).
__global__ void scatter_k(const int* __restrict__ src, const int* __restrict__ dst,
                          const float* __restrict__ ew, const float* __restrict__ dinv,
                          const int* __restrict__ offs, int* __restrict__ fill,
                          ushort* __restrict__ esrc, float* __restrict__ eww) {
    int e = blockIdx.x * 256 + threadIdx.x;
    if (e < E_) {
        int s = src[e], d = dst[e];
        int pos = offs[d] + atomicAdd(fill + d, 1);
        float w = -dinv[s] * ew[e] * dinv[d];
        esrc[pos] = (ushort)s;
        eww[pos]  = w;
    }
}

// ---------------------------------------------------------------- bf16 weight prep
__global__ void wprep_k(const float* __restrict__ cw, const float* __restrict__ w1,
                        const float* __restrict__ w2,
                        short* __restrict__ wtc, short* __restrict__ wt1,
                        short* __restrict__ wt2) {
    int idx = blockIdx.x * 256 + threadIdx.x;
    if (idx >= WTOT_) return;
    int b = idx / SZB_;
    int rem = idx - b * SZB_;
    if (rem < SZ1_) {
        int n = rem / 192, k = rem - n * 192;
        int part = k >> 6, c = k & 63;
        const float* base = cw + (size_t)b * 3 * 64 * 128;
        float v;
        if (part == 0)      v = base[c * 128 + n] - base[16384 + c * 128 + n];
        else if (part == 1) v = base[8192 + c * 128 + n];
        else                v = 2.f * base[16384 + c * 128 + n];
        wtc[(size_t)b * SZ1_ + n * 192 + k] = (short)bfr(v);
    } else if (rem < SZ1_ + SZ2_) {
        int r2 = rem - SZ1_;
        int n = r2 >> 7, k = r2 & 127;
        float v = w1[(size_t)b * 16384 + k * 128 + n];
        wt1[(size_t)b * SZ2_ + n * 128 + k] = (short)bfr(v);
    } else {
        int r3 = rem - SZ1_ - SZ2_;
        int n = r3 >> 7, k = r3 & 127;
        float v = w2[(size_t)b * 8192 + k * 64 + n];
        wt2[(size_t)b * SZ3_ + n * 128 + k] = (short)bfr(v);
    }
}

// ---------------------------------------------------------------- transposes
__global__ void transpose_in_k(const float* __restrict__ x, float* __restrict__ h,
                               ushort* __restrict__ hb) {
    int idx = blockIdx.x * 256 + threadIdx.x;
    int c4 = idx & 15;
    int nb = idx >> 4;        // n*B + b
    int b  = nb & (B_ - 1);
    int n  = nb >> 4;
    const float4 v = *(const float4*)(x + ((size_t)b * N_ + n) * C_ + (c4 << 2));
    *(float4*)(h + (size_t)nb * C_ + (c4 << 2)) = v;
    uint2 p;
    p.x = pack_bf2(v.x, v.y);
    p.y = pack_bf2(v.z, v.w);
    *(uint2*)(hb + (size_t)nb * C_ + (c4 << 2)) = p;
}

__global__ void transpose_out_k(const float* __restrict__ h, float* __restrict__ out) {
    int idx = blockIdx.x * 256 + threadIdx.x;
    int c4 = idx & 15;
    int nb = idx >> 4;
    int b  = nb & (B_ - 1);
    int n  = nb >> 4;
    const float4 v = *(const float4*)(h + (size_t)nb * C_ + (c4 << 2));
    *(float4*)(out + ((size_t)b * N_ + n) * C_ + (c4 << 2)) = v;
}

// ---------------------------------------------------------------- SpMM, phase-blocked
// XCD-pinned phases (r7): blockIdx % 8 selects the XCD (HW round-robin), and we
// give XCD x exactly phases {2x, 2x+1}, slot-ordered so phase 2x's 1250 chunks
// complete before 2x+1 starts. Each 2.56 MB phase gather slice is then fetched
// into exactly ONE XCD L2 once (was ~6-8 XCDs x 16 phases => ~240 MB of the
// 320 MB FETCH). Edge metadata is split u16-src + f32-w and lists are padded to
// %4 (pad entries src=0,w=0), so the inner loop is branch-free ushort4+float4.
__global__ __launch_bounds__(256) void spmm_ph_k(const ushort* __restrict__ in,
                                                 ushort* __restrict__ out,
                                                 const int* __restrict__ offs,
                                                 const ushort* __restrict__ esrc,
                                                 const float* __restrict__ eww,
                                                 const int* __restrict__ perm) {
    const int b    = blockIdx.x;
    const int xcd  = b & (NXCD_ - 1);
    const int slot = b >> 3;                    // 0..2499
    const int half = (slot >= NCHK_) ? 1 : 0;
    const int ph   = (xcd << 1) | half;
    const int chunk = slot - (half ? NCHK_ : 0);
    const int g      = threadIdx.x >> 4;
    const int lane16 = threadIdx.x & 15;
    const int n = perm[chunk * NPB_ + g];
    const int s0 = offs[n], s1 = offs[n + 1];
    const ushort* inp = in + (size_t)ph * PCOL_ + (lane16 << 2);

    float a0 = 0.f, a1 = 0.f, a2 = 0.f, a3 = 0.f;
    for (int i = s0; i < s1; i += 4) {
        ushort4 ss = *(const ushort4*)(esrc + i);
        float4  wf = *(const float4*)(eww + i);
        uint2 v0 = *(const uint2*)(inp + ((u32)ss.x << 10));
        uint2 v1 = *(const uint2*)(inp + ((u32)ss.y << 10));
        uint2 v2 = *(const uint2*)(inp + ((u32)ss.z << 10));
        uint2 v3 = *(const uint2*)(inp + ((u32)ss.w << 10));
        a0 += wf.x * bflo(v0.x) + wf.y * bflo(v1.x) + wf.z * bflo(v2.x) + wf.w * bflo(v3.x);
        a1 += wf.x * bfhi(v0.x) + wf.y * bfhi(v1.x) + wf.z * bfhi(v2.x) + wf.w * bfhi(v3.x);
        a2 += wf.x * bflo(v0.y) + wf.y * bflo(v1.y) + wf.z * bflo(v2.y) + wf.w * bflo(v3.y);
        a3 += wf.x * bfhi(v0.y) + wf.y * bfhi(v1.y) + wf.z * bfhi(v2.y) + wf.w * bfhi(v3.y);
    }
    uint2 p;
    p.x = pack_bf2(a0, a1);
    p.y = pack_bf2(a2, a3);
    *(uint2*)(out + (size_t)n * ROW_ + (size_t)ph * PCOL_ + (lane16 << 2)) = p;
}

// ---------------------------------------------------------------- MFMA MLP block
// Column-sliced wave partition (r6): each of the 4 waves owns 32/128 cols
// (16/64 for stage 3) across ALL 64 rows; weight fragments live in register
// arrays (batched loads). A-tile [64x192]=[hb|t1b|sb] reg-staged into LDS once;
// g1/g2 alias the same buffer between barriers. LDS 25600B, stride 200 shorts.
__global__ __launch_bounds__(256, 4) void mlp_mfma_k(
        float* __restrict__ h, ushort* __restrict__ hb,
        const ushort* __restrict__ t1b, const ushort* __restrict__ sb,
        const short* __restrict__ wtc, const short* __restrict__ wt1,
        const short* __restrict__ wt2,
        const float* __restrict__ cbias, const float* __restrict__ b1,
        const float* __restrict__ b2, const float* __restrict__ betap) {
    __shared__ __align__(16) short u[64 * LDP];

    const int tid  = threadIdx.x;
    const int wv   = tid >> 6;
    const int lane = tid & 63;
    const int m    = lane & 15;
    const int q    = lane >> 4;
    const int row0 = blockIdx.x * 64;
    const float sp    = __logf(1.f + __expf(betap[0]));
    const float inv11 = 1.0f / 1.1f;

    // ---- stage-1 weight fragments (12): cols n = wv*32 + t*16 + m, k = kb*32+q*8
    s16x8 wA[6][2];
#pragma unroll
    for (int kb = 0; kb < 6; ++kb)
#pragma unroll
        for (int t = 0; t < 2; ++t)
            wA[kb][t] = *(const s16x8*)(wtc + ((wv << 5) + (t << 4) + m) * 192
                                            + (kb << 5) + (q << 3));

    // ---- cooperative A-tile fill: [64 rows][192 cols] = [hb|t1b|sb], batched
    {
        const ushort* srcs[3] = { hb, t1b, sb };
        s16x8 tv[3][2];
#pragma unroll
        for (int s = 0; s < 3; ++s)
#pragma unroll
            for (int i = 0; i < 2; ++i) {
                int ck = tid + (i << 8);            // 0..511
                int r = ck >> 3, c8 = ck & 7;
                tv[s][i] = *(const s16x8*)(srcs[s] + (size_t)(row0 + r) * C_ + (c8 << 3));
            }
#pragma unroll
        for (int s = 0; s < 3; ++s)
#pragma unroll
            for (int i = 0; i < 2; ++i) {
                int ck = tid + (i << 8);
                int r = ck >> 3, c8 = ck & 7;
                *(s16x8*)(u + r * LDP + (s << 6) + (c8 << 3)) = tv[s][i];
            }
    }
    __syncthreads();

    // ---- stage 1: A(64x192) @ Wc^T-slice -> acc[rg][t] (64 rows x 32 cols/wave)
    f32x4 acc[4][2];
#pragma unroll
    for (int rg = 0; rg < 4; ++rg)
#pragma unroll
        for (int t = 0; t < 2; ++t) acc[rg][t] = (f32x4){0.f, 0.f, 0.f, 0.f};
#pragma unroll
    for (int kb = 0; kb < 6; ++kb)
#pragma unroll
        for (int rg = 0; rg < 4; ++rg) {
            s16x8 af = *(const s16x8*)(u + ((rg << 4) + m) * LDP + (kb << 5) + (q << 3));
            acc[rg][0] = __builtin_amdgcn_mfma_f32_16x16x32_bf16(af, wA[kb][0], acc[rg][0], 0, 0, 0);
            acc[rg][1] = __builtin_amdgcn_mfma_f32_16x16x32_bf16(af, wA[kb][1], acc[rg][1], 0, 0, 0);
        }
    __syncthreads();   // all waves done reading A-tile; u now becomes g1

    // stage-2 weight prefetch (overlaps epilogue-1 VALU; wA is dead now)
    s16x8 wB[4][2];
#pragma unroll
    for (int k4 = 0; k4 < 4; ++k4)
#pragma unroll
        for (int t = 0; t < 2; ++t)
            wB[k4][t] = *(const s16x8*)(wt1 + (((wv << 5) + (t << 4) + m) << 7)
                                            + (k4 << 5) + (q << 3));

    // ---- epilogue 1: bias + swish -> g1 (cols wv*32..wv*32+31, all 64 rows)
    {
        float cb0 = cbias[(wv << 5) + m];
        float cb1 = cbias[(wv << 5) + 16 + m];
#pragma unroll
        for (int rg = 0; rg < 4; ++rg)
#pragma unroll
            for (int t = 0; t < 2; ++t) {
                float bv = t ? cb1 : cb0;
#pragma unroll
                for (int r = 0; r < 4; ++r) {
                    float o = acc[rg][t][r] + bv;
                    float g = o * (1.f / (1.f + __expf(-o * sp))) * inv11;
                    u[((rg << 4) + (q << 2) + r) * LDP + (wv << 5) + (t << 4) + m] =
                        (short)bfr(g);
                }
            }
    }
    __syncthreads();

    // ---- stage 2: g1(64x128) @ w1^T-slice
    f32x4 acc2[4][2];
#pragma unroll
    for (int rg = 0; rg < 4; ++rg)
#pragma unroll
        for (int t = 0; t < 2; ++t) acc2[rg][t] = (f32x4){0.f, 0.f, 0.f, 0.f};
#pragma unroll
    for (int k4 = 0; k4 < 4; ++k4)
#pragma unroll
        for (int rg = 0; rg < 4; ++rg) {
            s16x8 af = *(const s16x8*)(u + ((rg << 4) + m) * LDP + (k4 << 5) + (q << 3));
            acc2[rg][0] = __builtin_amdgcn_mfma_f32_16x16x32_bf16(af, wB[k4][0], acc2[rg][0], 0, 0, 0);
            acc2[rg][1] = __builtin_amdgcn_mfma_f32_16x16x32_bf16(af, wB[k4][1], acc2[rg][1], 0, 0, 0);
        }
    __syncthreads();   // all waves done reading g1; u now becomes g2

    // stage-3 weight prefetch (overlaps epilogue-2 VALU)
    s16x8 wC[4];
#pragma unroll
    for (int k4 = 0; k4 < 4; ++k4)
        wC[k4] = *(const s16x8*)(wt2 + (((wv << 4) + m) << 7) + (k4 << 5) + (q << 3));

    // ---- epilogue 2: bias + swish -> g2
    {
        float b10 = b1[(wv << 5) + m];
        float b11 = b1[(wv << 5) + 16 + m];
#pragma unroll
        for (int rg = 0; rg < 4; ++rg)
#pragma unroll
            for (int t = 0; t < 2; ++t) {
                float bv = t ? b11 : b10;
#pragma unroll
                for (int r = 0; r < 4; ++r) {
                    float o = acc2[rg][t][r] + bv;
                    float g = o * (1.f / (1.f + __expf(-o * sp))) * inv11;
                    u[((rg << 4) + (q << 2) + r) * LDP + (wv << 5) + (t << 4) + m] =
                        (short)bfr(g);
                }
            }
    }
    __syncthreads();

    // ---- stage 3: g2(64x128) @ w2^T-slice -> 16 cols/wave
    f32x4 acc3[4];
#pragma unroll
    for (int rg = 0; rg < 4; ++rg) acc3[rg] = (f32x4){0.f, 0.f, 0.f, 0.f};
#pragma unroll
    for (int k4 = 0; k4 < 4; ++k4)
#pragma unroll
        for (int rg = 0; rg < 4; ++rg) {
            s16x8 af = *(const s16x8*)(u + ((rg << 4) + m) * LDP + (k4 << 5) + (q << 3));
            acc3[rg] = __builtin_amdgcn_mfma_f32_16x16x32_bf16(af, wC[k4], acc3[rg], 0, 0, 0);
        }

    // ---- epilogue 3: residual h += f (batched h loads), refresh hb
    {
        float b2v = b2[(wv << 4) + m];
        float hv[4][4];
#pragma unroll
        for (int rg = 0; rg < 4; ++rg)
#pragma unroll
            for (int r = 0; r < 4; ++r)
                hv[rg][r] = h[(size_t)(row0 + (rg << 4) + (q << 2) + r) * C_
                              + (wv << 4) + m];
#pragma unroll
        for (int rg = 0; rg < 4; ++rg)
#pragma unroll
            for (int r = 0; r < 4; ++r) {
                size_t eidx = (size_t)(row0 + (rg << 4) + (q << 2) + r) * C_
                              + (wv << 4) + m;
                float nv = hv[rg][r] + acc3[rg][r] + b2v;
                h[eidx]  = nv;
                hb[eidx] = (ushort)bfr(nv);
            }
    }
}

// ---------------------------------------------------------------- launch
extern "C" void kernel_launch(void* const* d_in, const int* in_sizes, int n_in,
                              void* d_out, int out_size, void* d_ws, size_t ws_size,
                              hipStream_t stream) {
    const float* x    = (const float*)d_in[0];
    const int*   ei   = (const int*)d_in[1];
    const float* ew   = (const float*)d_in[2];
    const float* cw   = (const float*)d_in[3];
    const float* cb   = (const float*)d_in[4];
    const float* beta = (const float*)d_in[5];
    const float* w1   = (const float*)d_in[6];
    const float* b1   = (const float*)d_in[7];
    const float* w2   = (const float*)d_in[8];
    const float* b2   = (const float*)d_in[9];
    float* out = (float*)d_out;

    char* ws = (char*)d_ws;
    float*  h_t  = (float*) (ws + OFF_H);
    ushort* hb   = (ushort*)(ws + OFF_HB);
    ushort* t1b  = (ushort*)(ws + OFF_T1B);
    ushort* sb   = (ushort*)(ws + OFF_SB);
    float*  deg  = (float*) (ws + OFF_DEG);
    int*    cnt  = (int*)   (ws + OFF_CNT);
    int*    offs = (int*)   (ws + OFF_OFFS);
    ushort* esrc = (ushort*)(ws + OFF_ESRC);
    float*  eww  = (float*) (ws + OFF_EW);
    int*    perm = (int*)   (ws + OFF_PERM);
    int*    hist = (int*)   (ws + OFF_HIST);
    int*    hoff = (int*)   (ws + OFF_HOFF);
    int*    hfil = (int*)   (ws + OFF_HFIL);
    short*  wtc  = (short*) (ws + OFF_WTC);
    short*  wt1  = (short*) (ws + OFF_WT1);
    short*  wt2  = (short*) (ws + OFF_WT2);

    const int* srcI = ei;
    const int* dstI = ei + E_;

    // graph prep
    hipMemsetAsync(deg, 0, (size_t)N_ * 4, stream);
    hipMemsetAsync(cnt, 0, (size_t)N_ * 4, stream);
    hipMemsetAsync(hist, 0, (size_t)NBIN_ * 4, stream);
    hipMemsetAsync(hfil, 0, (size_t)NBIN_ * 4, stream);
    hipMemsetAsync(esrc, 0, (size_t)EP_ * 2, stream);   // pad entries: src=0
    hipMemsetAsync(eww,  0, (size_t)EP_ * 4, stream);   // pad entries: w=0
    deg_cnt_k<<<(E_ + 255) / 256, 256, 0, stream>>>(srcI, dstI, ew, deg, cnt);
    dinv_k<<<(N_ + 255) / 256, 256, 0, stream>>>(deg);
    scan_k<<<1, 1024, 0, stream>>>(cnt, offs);
    hist_k<<<(N_ + 255) / 256, 256, 0, stream>>>(cnt, hist);
    hscan_k<<<1, NBIN_, 0, stream>>>(hist, hoff);
    permscatter_k<<<(N_ + 255) / 256, 256, 0, stream>>>(cnt, hoff, hfil, perm);
    hipMemsetAsync(cnt, 0, (size_t)N_ * 4, stream);
    scatter_k<<<(E_ + 255) / 256, 256, 0, stream>>>(srcI, dstI, ew, deg, offs, cnt,
                                                    esrc, eww);

    // bf16 weights
    wprep_k<<<(WTOT_ + 255) / 256, 256, 0, stream>>>(cw, w1, w2, wtc, wt1, wt2);

    // x -> [N,B,C] (fp32 + bf16 image)
    transpose_in_k<<<(N_ * B_ * 16) / 256, 256, 0, stream>>>(x, h_t, hb);

    for (int b = 0; b < NB_; ++b) {
        spmm_ph_k<<<PH_ * NCHK_, 256, 0, stream>>>(hb, t1b, offs, esrc, eww, perm);
        spmm_ph_k<<<PH_ * NCHK_, 256, 0, stream>>>(t1b, sb, offs, esrc, eww, perm);
        mlp_mfma_k<<<NR_ / 64, 256, 0, stream>>>(h_t, hb, t1b, sb,
                                                 wtc + (size_t)b * SZ1_,
                                                 wt1 + (size_t)b * SZ2_,
                                                 wt2 + (size_t)b * SZ3_,
                                                 cb + (size_t)b * DIM_,
                                                 b1 + (size_t)b * DIM_,
                                                 b2 + (size_t)b * C_,
                                                 beta + b);
    }

    // [N,B,C] -> out
    transpose_out_k<<<(N_ * B_ * 16) / 256, 256, 0, stream>>>(h_t, out);
}

// Round 3
// 1365.042 us; speedup vs baseline: 1.4331x; 1.0285x over previous
//
#include <hip/hip_runtime.h>

// ---------------------------------------------------------------- constants
namespace {
constexpr int   B_   = 16;
constexpr int   N_   = 20000;
constexpr int   C_   = 64;
constexpr int   DIM_ = 128;
constexpr int   E_   = 640000;
constexpr int   NB_  = 3;
constexpr int   ROW_ = B_ * C_;      // 1024 elements per node row in [N,B,C]
constexpr int   NR_  = N_ * B_;      // 320000 rows of C elements

constexpr int   LDP  = 200;          // LDS row stride (shorts): 400B = 100 dwords,
                                     // 100 % 32 = 4 -> 2-way max on b128 reads (free)

// SpMM phase blocking
constexpr int   PH_   = 16;          // phases
constexpr int   PCOL_ = ROW_ / PH_;  // 64 cols (128B) per phase
constexpr int   NPB_  = 16;          // nodes per block (16 lanes each)
constexpr int   NCHK_ = N_ / NPB_;   // 1250 chunks per phase
constexpr int   NBIN_ = 1024;        // degree-sort bins
constexpr int   NXCD_ = 8;           // XCDs; blockIdx % 8 -> XCD (round-robin)
constexpr int   EP_   = E_ + 7 * N_ + 64;   // padded edge capacity (lists %8)

// bf16 weight region sizes (elements)
constexpr int   SZ1_ = 128 * 192;    // Wc^T  per block
constexpr int   SZ2_ = 128 * 128;    // w1^T  per block
constexpr int   SZ3_ = 64 * 128;     // w2^T  per block
constexpr int   SZB_ = SZ1_ + SZ2_ + SZ3_;
constexpr int   WTOT_ = NB_ * SZB_;

// workspace layout (bytes)
constexpr size_t SZH_  = (size_t)N_ * ROW_ * sizeof(float);   // fp32 h
constexpr size_t SZHB_ = (size_t)N_ * ROW_ * 2;               // bf16 row image
constexpr size_t OFF_H    = 0;
constexpr size_t OFF_HB   = SZH_;
constexpr size_t OFF_T1B  = OFF_HB  + SZHB_;
constexpr size_t OFF_SB   = OFF_T1B + SZHB_;
constexpr size_t OFF_DEG  = OFF_SB  + SZHB_;
constexpr size_t OFF_CNT  = OFF_DEG + (size_t)N_ * 4;
constexpr size_t OFF_OFFS = OFF_CNT + (size_t)N_ * 4;
constexpr size_t OFF_CV   = ((OFF_OFFS + (size_t)(N_ + 1) * 4 + 255) / 256) * 256;
// esrc (u16[EP_]) + eww (f32[EP_]) live inside the old 8B-cv footprint
constexpr size_t OFF_ESRC = OFF_CV;
constexpr size_t OFF_EW   = ((OFF_ESRC + (size_t)EP_ * 2 + 255) / 256) * 256;
static_assert(OFF_EW + (size_t)EP_ * 4 <= OFF_CV + (size_t)E_ * 8, "cv region overflow");
constexpr size_t OFF_PERM = OFF_CV   + (size_t)E_ * 8;
constexpr size_t OFF_HIST = OFF_PERM + (size_t)N_ * 4;
constexpr size_t OFF_HOFF = OFF_HIST + (size_t)NBIN_ * 4;
constexpr size_t OFF_HFIL = OFF_HOFF + (size_t)NBIN_ * 4;
constexpr size_t OFF_WTC  = OFF_HFIL + (size_t)NBIN_ * 4;
constexpr size_t OFF_WT1  = OFF_WTC + (size_t)NB_ * SZ1_ * 2;
constexpr size_t OFF_WT2  = OFF_WT1 + (size_t)NB_ * SZ2_ * 2;
// total ~210 MB
} // namespace

typedef short s16x8 __attribute__((ext_vector_type(8)));
typedef float f32x4 __attribute__((ext_vector_type(4)));
typedef unsigned int u32;

__device__ __forceinline__ u32 bfr(float x) {
    u32 u = __float_as_uint(x);
    return (u + 0x7FFFu + ((u >> 16) & 1u)) >> 16;
}
__device__ __forceinline__ u32 pack_bf2(float x, float y) {
    return bfr(x) | (bfr(y) << 16);
}
__device__ __forceinline__ float bflo(u32 u) { return __uint_as_float(u << 16); }
__device__ __forceinline__ float bfhi(u32 u) { return __uint_as_float(u & 0xFFFF0000u); }

// ---------------------------------------------------------------- graph prep
__global__ void deg_cnt_k(const int* __restrict__ src, const int* __restrict__ dst,
                          const float* __restrict__ ew,
                          float* __restrict__ deg, int* __restrict__ cnt) {
    int e = blockIdx.x * 256 + threadIdx.x;
    if (e < E_) {
        atomicAdd(deg + src[e], ew[e]);
        atomicAdd(cnt + dst[e], 1);
    }
}

__global__ void dinv_k(float* __restrict__ deg) {
    int i = blockIdx.x * 256 + threadIdx.x;
    if (i < N_) {
        float d = deg[i];
        deg[i] = (d > 0.f) ? rsqrtf(fmaxf(d, 1e-12f)) : 0.f;
    }
}

// exclusive scan of per-node counts PADDED to multiples of 8 (branch-free spmm)
__global__ __launch_bounds__(1024) void scan_k(const int* __restrict__ cnt,
                                               int* __restrict__ offs) {
    __shared__ int sums[1024];
    const int tid = threadIdx.x;
    constexpr int CH = (N_ + 1023) / 1024;   // 20
    const int base = tid * CH;
    int local = 0;
    for (int j = 0; j < CH; ++j) {
        int i = base + j;
        if (i < N_) local += (cnt[i] + 7) & ~7;
    }
    sums[tid] = local;
    __syncthreads();
    for (int off = 1; off < 1024; off <<= 1) {
        int v = sums[tid];
        int u = (tid >= off) ? sums[tid - off] : 0;
        __syncthreads();
        sums[tid] = v + u;
        __syncthreads();
    }
    int run = (tid > 0) ? sums[tid - 1] : 0;
    for (int j = 0; j < CH; ++j) {
        int i = base + j;
        if (i < N_) { offs[i] = run; run += (cnt[i] + 7) & ~7; }
    }
    if (tid == 1023) offs[N_] = sums[1023];
}

// degree histogram / scan / perm-scatter (degree-sorted node order)
__global__ void hist_k(const int* __restrict__ cnt, int* __restrict__ hist) {
    int i = blockIdx.x * 256 + threadIdx.x;
    if (i < N_) atomicAdd(hist + min(cnt[i], NBIN_ - 1), 1);
}

__global__ __launch_bounds__(1024) void hscan_k(const int* __restrict__ hist,
                                                int* __restrict__ hoffs) {
    __shared__ int s[NBIN_];
    int t = threadIdx.x;
    s[t] = hist[t];
    __syncthreads();
    for (int off = 1; off < NBIN_; off <<= 1) {
        int v = s[t];
        int u = (t >= off) ? s[t - off] : 0;
        __syncthreads();
        s[t] = v + u;
        __syncthreads();
    }
    hoffs[t] = (t > 0) ? s[t - 1] : 0;
}

__global__ void permscatter_k(const int* __restrict__ cnt, const int* __restrict__ hoffs,
                              int* __restrict__ hfill, int* __restrict__ perm) {
    int i = blockIdx.x * 256 + threadIdx.x;
    if (i < N_) {
        int b = min(cnt[i], NBIN_ - 1);
        int pos = hoffs[b] + atomicAdd(hfill + b, 1);
        perm[pos] = i;
    }
}

// split edge store: u16 src + f32 weight (6B/edge, was 8B). pads stay 0 (memset).
__global__ void scatter_k(const int* __restrict__ src, const int* __restrict__ dst,
                          const float* __restrict__ ew, const float* __restrict__ dinv,
                          const int* __restrict__ offs, int* __restrict__ fill,
                          ushort* __restrict__ esrc, float* __restrict__ eww) {
    int e = blockIdx.x * 256 + threadIdx.x;
    if (e < E_) {
        int s = src[e], d = dst[e];
        int pos = offs[d] + atomicAdd(fill + d, 1);
        float w = -dinv[s] * ew[e] * dinv[d];
        esrc[pos] = (ushort)s;
        eww[pos]  = w;
    }
}

// ---------------------------------------------------------------- bf16 weight prep
__global__ void wprep_k(const float* __restrict__ cw, const float* __restrict__ w1,
                        const float* __restrict__ w2,
                        short* __restrict__ wtc, short* __restrict__ wt1,
                        short* __restrict__ wt2) {
    int idx = blockIdx.x * 256 + threadIdx.x;
    if (idx >= WTOT_) return;
    int b = idx / SZB_;
    int rem = idx - b * SZB_;
    if (rem < SZ1_) {
        int n = rem / 192, k = rem - n * 192;
        int part = k >> 6, c = k & 63;
        const float* base = cw + (size_t)b * 3 * 64 * 128;
        float v;
        if (part == 0)      v = base[c * 128 + n] - base[16384 + c * 128 + n];
        else if (part == 1) v = base[8192 + c * 128 + n];
        else                v = 2.f * base[16384 + c * 128 + n];
        wtc[(size_t)b * SZ1_ + n * 192 + k] = (short)bfr(v);
    } else if (rem < SZ1_ + SZ2_) {
        int r2 = rem - SZ1_;
        int n = r2 >> 7, k = r2 & 127;
        float v = w1[(size_t)b * 16384 + k * 128 + n];
        wt1[(size_t)b * SZ2_ + n * 128 + k] = (short)bfr(v);
    } else {
        int r3 = rem - SZ1_ - SZ2_;
        int n = r3 >> 7, k = r3 & 127;
        float v = w2[(size_t)b * 8192 + k * 64 + n];
        wt2[(size_t)b * SZ3_ + n * 128 + k] = (short)bfr(v);
    }
}

// ---------------------------------------------------------------- transposes
__global__ void transpose_in_k(const float* __restrict__ x, float* __restrict__ h,
                               ushort* __restrict__ hb) {
    int idx = blockIdx.x * 256 + threadIdx.x;
    int c4 = idx & 15;
    int nb = idx >> 4;        // n*B + b
    int b  = nb & (B_ - 1);
    int n  = nb >> 4;
    const float4 v = *(const float4*)(x + ((size_t)b * N_ + n) * C_ + (c4 << 2));
    *(float4*)(h + (size_t)nb * C_ + (c4 << 2)) = v;
    uint2 p;
    p.x = pack_bf2(v.x, v.y);
    p.y = pack_bf2(v.z, v.w);
    *(uint2*)(hb + (size_t)nb * C_ + (c4 << 2)) = p;
}

__global__ void transpose_out_k(const float* __restrict__ h, float* __restrict__ out) {
    int idx = blockIdx.x * 256 + threadIdx.x;
    int c4 = idx & 15;
    int nb = idx >> 4;
    int b  = nb & (B_ - 1);
    int n  = nb >> 4;
    const float4 v = *(const float4*)(h + (size_t)nb * C_ + (c4 << 2));
    *(float4*)(out + ((size_t)b * N_ + n) * C_ + (c4 << 2)) = v;
}

// ---------------------------------------------------------------- SpMM, phase-blocked
// XCD-pinned phases (r7) + software-pipelined edge loop (r8). blockIdx % 8
// selects the XCD; XCD x runs phases {2x, 2x+1} so each 2.56 MB gather slice is
// fetched into one XCD L2 once. Edge lists padded to %8 (pads src=0,w=0). Per
// iteration: 8 gathers issued from already-resident metadata, then NEXT
// iteration's metadata (uint4 + 2x float4) is issued before the FMA block, so
// its latency hides under the 32 FMAs -> single-round-trip critical path (the
// r7 loop had meta->gather serial chains and sat at 38% VALUBusy, VGPR=20).
__global__ __launch_bounds__(256) void spmm_ph_k(const ushort* __restrict__ in,
                                                 ushort* __restrict__ out,
                                                 const int* __restrict__ offs,
                                                 const ushort* __restrict__ esrc,
                                                 const float* __restrict__ eww,
                                                 const int* __restrict__ perm) {
    const int b    = blockIdx.x;
    const int xcd  = b & (NXCD_ - 1);
    const int slot = b >> 3;                    // 0..2499
    const int half = (slot >= NCHK_) ? 1 : 0;
    const int ph   = (xcd << 1) | half;
    const int chunk = slot - (half ? NCHK_ : 0);
    const int g      = threadIdx.x >> 4;
    const int lane16 = threadIdx.x & 15;
    const int n = perm[chunk * NPB_ + g];
    const int s0 = offs[n], s1 = offs[n + 1];
    const ushort* inp = in + (size_t)ph * PCOL_ + (lane16 << 2);

    float a0 = 0.f, a1 = 0.f, a2 = 0.f, a3 = 0.f;
    if (s0 < s1) {
        uint4  sp = *(const uint4*)(esrc + s0);      // 8 x u16 src
        float4 w0 = *(const float4*)(eww + s0);
        float4 w1 = *(const float4*)(eww + s0 + 4);
        for (int i = s0; i < s1; ) {
            const int inext = i + 8;
            uint2 v0 = *(const uint2*)(inp + ((sp.x & 0xFFFFu) << 10));
            uint2 v1 = *(const uint2*)(inp + ((sp.x >> 16)     << 10));
            uint2 v2 = *(const uint2*)(inp + ((sp.y & 0xFFFFu) << 10));
            uint2 v3 = *(const uint2*)(inp + ((sp.y >> 16)     << 10));
            uint2 v4 = *(const uint2*)(inp + ((sp.z & 0xFFFFu) << 10));
            uint2 v5 = *(const uint2*)(inp + ((sp.z >> 16)     << 10));
            uint2 v6 = *(const uint2*)(inp + ((sp.w & 0xFFFFu) << 10));
            uint2 v7 = *(const uint2*)(inp + ((sp.w >> 16)     << 10));
            // prefetch next metadata (reads stay inside padded EP_ region)
            uint4  sp_n = *(const uint4*)(esrc + inext);
            float4 w0_n = *(const float4*)(eww + inext);
            float4 w1_n = *(const float4*)(eww + inext + 4);
            a0 += w0.x * bflo(v0.x) + w0.y * bflo(v1.x) + w0.z * bflo(v2.x) + w0.w * bflo(v3.x)
                + w1.x * bflo(v4.x) + w1.y * bflo(v5.x) + w1.z * bflo(v6.x) + w1.w * bflo(v7.x);
            a1 += w0.x * bfhi(v0.x) + w0.y * bfhi(v1.x) + w0.z * bfhi(v2.x) + w0.w * bfhi(v3.x)
                + w1.x * bfhi(v4.x) + w1.y * bfhi(v5.x) + w1.z * bfhi(v6.x) + w1.w * bfhi(v7.x);
            a2 += w0.x * bflo(v0.y) + w0.y * bflo(v1.y) + w0.z * bflo(v2.y) + w0.w * bflo(v3.y)
                + w1.x * bflo(v4.y) + w1.y * bflo(v5.y) + w1.z * bflo(v6.y) + w1.w * bflo(v7.y);
            a3 += w0.x * bfhi(v0.y) + w0.y * bfhi(v1.y) + w0.z * bfhi(v2.y) + w0.w * bfhi(v3.y)
                + w1.x * bfhi(v4.y) + w1.y * bfhi(v5.y) + w1.z * bfhi(v6.y) + w1.w * bfhi(v7.y);
            sp = sp_n; w0 = w0_n; w1 = w1_n;
            i = inext;
        }
    }
    uint2 p;
    p.x = pack_bf2(a0, a1);
    p.y = pack_bf2(a2, a3);
    *(uint2*)(out + (size_t)n * ROW_ + (size_t)ph * PCOL_ + (lane16 << 2)) = p;
}

// ---------------------------------------------------------------- MFMA MLP block
// Column-sliced wave partition (r6): each of the 4 waves owns 32/128 cols
// (16/64 for stage 3) across ALL 64 rows; weight fragments live in register
// arrays (batched loads). A-tile [64x192]=[hb|t1b|sb] reg-staged into LDS once;
// g1/g2 alias the same buffer between barriers. LDS 25600B, stride 200 shorts.
__global__ __launch_bounds__(256, 4) void mlp_mfma_k(
        float* __restrict__ h, ushort* __restrict__ hb,
        const ushort* __restrict__ t1b, const ushort* __restrict__ sb,
        const short* __restrict__ wtc, const short* __restrict__ wt1,
        const short* __restrict__ wt2,
        const float* __restrict__ cbias, const float* __restrict__ b1,
        const float* __restrict__ b2, const float* __restrict__ betap) {
    __shared__ __align__(16) short u[64 * LDP];

    const int tid  = threadIdx.x;
    const int wv   = tid >> 6;
    const int lane = tid & 63;
    const int m    = lane & 15;
    const int q    = lane >> 4;
    const int row0 = blockIdx.x * 64;
    const float sp    = __logf(1.f + __expf(betap[0]));
    const float inv11 = 1.0f / 1.1f;

    // ---- stage-1 weight fragments (12): cols n = wv*32 + t*16 + m, k = kb*32+q*8
    s16x8 wA[6][2];
#pragma unroll
    for (int kb = 0; kb < 6; ++kb)
#pragma unroll
        for (int t = 0; t < 2; ++t)
            wA[kb][t] = *(const s16x8*)(wtc + ((wv << 5) + (t << 4) + m) * 192
                                            + (kb << 5) + (q << 3));

    // ---- cooperative A-tile fill: [64 rows][192 cols] = [hb|t1b|sb], batched
    {
        const ushort* srcs[3] = { hb, t1b, sb };
        s16x8 tv[3][2];
#pragma unroll
        for (int s = 0; s < 3; ++s)
#pragma unroll
            for (int i = 0; i < 2; ++i) {
                int ck = tid + (i << 8);            // 0..511
                int r = ck >> 3, c8 = ck & 7;
                tv[s][i] = *(const s16x8*)(srcs[s] + (size_t)(row0 + r) * C_ + (c8 << 3));
            }
#pragma unroll
        for (int s = 0; s < 3; ++s)
#pragma unroll
            for (int i = 0; i < 2; ++i) {
                int ck = tid + (i << 8);
                int r = ck >> 3, c8 = ck & 7;
                *(s16x8*)(u + r * LDP + (s << 6) + (c8 << 3)) = tv[s][i];
            }
    }
    __syncthreads();

    // ---- stage 1: A(64x192) @ Wc^T-slice -> acc[rg][t] (64 rows x 32 cols/wave)
    f32x4 acc[4][2];
#pragma unroll
    for (int rg = 0; rg < 4; ++rg)
#pragma unroll
        for (int t = 0; t < 2; ++t) acc[rg][t] = (f32x4){0.f, 0.f, 0.f, 0.f};
#pragma unroll
    for (int kb = 0; kb < 6; ++kb)
#pragma unroll
        for (int rg = 0; rg < 4; ++rg) {
            s16x8 af = *(const s16x8*)(u + ((rg << 4) + m) * LDP + (kb << 5) + (q << 3));
            acc[rg][0] = __builtin_amdgcn_mfma_f32_16x16x32_bf16(af, wA[kb][0], acc[rg][0], 0, 0, 0);
            acc[rg][1] = __builtin_amdgcn_mfma_f32_16x16x32_bf16(af, wA[kb][1], acc[rg][1], 0, 0, 0);
        }
    __syncthreads();   // all waves done reading A-tile; u now becomes g1

    // stage-2 weight prefetch (overlaps epilogue-1 VALU; wA is dead now)
    s16x8 wB[4][2];
#pragma unroll
    for (int k4 = 0; k4 < 4; ++k4)
#pragma unroll
        for (int t = 0; t < 2; ++t)
            wB[k4][t] = *(const s16x8*)(wt1 + (((wv << 5) + (t << 4) + m) << 7)
                                            + (k4 << 5) + (q << 3));

    // ---- epilogue 1: bias + swish -> g1 (cols wv*32..wv*32+31, all 64 rows)
    {
        float cb0 = cbias[(wv << 5) + m];
        float cb1 = cbias[(wv << 5) + 16 + m];
#pragma unroll
        for (int rg = 0; rg < 4; ++rg)
#pragma unroll
            for (int t = 0; t < 2; ++t) {
                float bv = t ? cb1 : cb0;
#pragma unroll
                for (int r = 0; r < 4; ++r) {
                    float o = acc[rg][t][r] + bv;
                    float g = o * (1.f / (1.f + __expf(-o * sp))) * inv11;
                    u[((rg << 4) + (q << 2) + r) * LDP + (wv << 5) + (t << 4) + m] =
                        (short)bfr(g);
                }
            }
    }
    __syncthreads();

    // ---- stage 2: g1(64x128) @ w1^T-slice
    f32x4 acc2[4][2];
#pragma unroll
    for (int rg = 0; rg < 4; ++rg)
#pragma unroll
        for (int t = 0; t < 2; ++t) acc2[rg][t] = (f32x4){0.f, 0.f, 0.f, 0.f};
#pragma unroll
    for (int k4 = 0; k4 < 4; ++k4)
#pragma unroll
        for (int rg = 0; rg < 4; ++rg) {
            s16x8 af = *(const s16x8*)(u + ((rg << 4) + m) * LDP + (k4 << 5) + (q << 3));
            acc2[rg][0] = __builtin_amdgcn_mfma_f32_16x16x32_bf16(af, wB[k4][0], acc2[rg][0], 0, 0, 0);
            acc2[rg][1] = __builtin_amdgcn_mfma_f32_16x16x32_bf16(af, wB[k4][1], acc2[rg][1], 0, 0, 0);
        }
    __syncthreads();   // all waves done reading g1; u now becomes g2

    // stage-3 weight prefetch (overlaps epilogue-2 VALU)
    s16x8 wC[4];
#pragma unroll
    for (int k4 = 0; k4 < 4; ++k4)
        wC[k4] = *(const s16x8*)(wt2 + (((wv << 4) + m) << 7) + (k4 << 5) + (q << 3));

    // ---- epilogue 2: bias + swish -> g2
    {
        float b10 = b1[(wv << 5) + m];
        float b11 = b1[(wv << 5) + 16 + m];
#pragma unroll
        for (int rg = 0; rg < 4; ++rg)
#pragma unroll
            for (int t = 0; t < 2; ++t) {
                float bv = t ? b11 : b10;
#pragma unroll
                for (int r = 0; r < 4; ++r) {
                    float o = acc2[rg][t][r] + bv;
                    float g = o * (1.f / (1.f + __expf(-o * sp))) * inv11;
                    u[((rg << 4) + (q << 2) + r) * LDP + (wv << 5) + (t << 4) + m] =
                        (short)bfr(g);
                }
            }
    }
    __syncthreads();

    // ---- stage 3: g2(64x128) @ w2^T-slice -> 16 cols/wave
    f32x4 acc3[4];
#pragma unroll
    for (int rg = 0; rg < 4; ++rg) acc3[rg] = (f32x4){0.f, 0.f, 0.f, 0.f};
#pragma unroll
    for (int k4 = 0; k4 < 4; ++k4)
#pragma unroll
        for (int rg = 0; rg < 4; ++rg) {
            s16x8 af = *(const s16x8*)(u + ((rg << 4) + m) * LDP + (k4 << 5) + (q << 3));
            acc3[rg] = __builtin_amdgcn_mfma_f32_16x16x32_bf16(af, wC[k4], acc3[rg], 0, 0, 0);
        }

    // ---- epilogue 3: residual h += f (batched h loads), refresh hb
    {
        float b2v = b2[(wv << 4) + m];
        float hv[4][4];
#pragma unroll
        for (int rg = 0; rg < 4; ++rg)
#pragma unroll
            for (int r = 0; r < 4; ++r)
                hv[rg][r] = h[(size_t)(row0 + (rg << 4) + (q << 2) + r) * C_
                              + (wv << 4) + m];
#pragma unroll
        for (int rg = 0; rg < 4; ++rg)
#pragma unroll
            for (int r = 0; r < 4; ++r) {
                size_t eidx = (size_t)(row0 + (rg << 4) + (q << 2) + r) * C_
                              + (wv << 4) + m;
                float nv = hv[rg][r] + acc3[rg][r] + b2v;
                h[eidx]  = nv;
                hb[eidx] = (ushort)bfr(nv);
            }
    }
}

// ---------------------------------------------------------------- launch
extern "C" void kernel_launch(void* const* d_in, const int* in_sizes, int n_in,
                              void* d_out, int out_size, void* d_ws, size_t ws_size,
                              hipStream_t stream) {
    const float* x    = (const float*)d_in[0];
    const int*   ei   = (const int*)d_in[1];
    const float* ew   = (const float*)d_in[2];
    const float* cw   = (const float*)d_in[3];
    const float* cb   = (const float*)d_in[4];
    const float* beta = (const float*)d_in[5];
    const float* w1   = (const float*)d_in[6];
    const float* b1   = (const float*)d_in[7];
    const float* w2   = (const float*)d_in[8];
    const float* b2   = (const float*)d_in[9];
    float* out = (float*)d_out;

    char* ws = (char*)d_ws;
    float*  h_t  = (float*) (ws + OFF_H);
    ushort* hb   = (ushort*)(ws + OFF_HB);
    ushort* t1b  = (ushort*)(ws + OFF_T1B);
    ushort* sb   = (ushort*)(ws + OFF_SB);
    float*  deg  = (float*) (ws + OFF_DEG);
    int*    cnt  = (int*)   (ws + OFF_CNT);
    int*    offs = (int*)   (ws + OFF_OFFS);
    ushort* esrc = (ushort*)(ws + OFF_ESRC);
    float*  eww  = (float*) (ws + OFF_EW);
    int*    perm = (int*)   (ws + OFF_PERM);
    int*    hist = (int*)   (ws + OFF_HIST);
    int*    hoff = (int*)   (ws + OFF_HOFF);
    int*    hfil = (int*)   (ws + OFF_HFIL);
    short*  wtc  = (short*) (ws + OFF_WTC);
    short*  wt1  = (short*) (ws + OFF_WT1);
    short*  wt2  = (short*) (ws + OFF_WT2);

    const int* srcI = ei;
    const int* dstI = ei + E_;

    // graph prep
    hipMemsetAsync(deg, 0, (size_t)N_ * 4, stream);
    hipMemsetAsync(cnt, 0, (size_t)N_ * 4, stream);
    hipMemsetAsync(hist, 0, (size_t)NBIN_ * 4, stream);
    hipMemsetAsync(hfil, 0, (size_t)NBIN_ * 4, stream);
    hipMemsetAsync(esrc, 0, (size_t)EP_ * 2, stream);   // pad entries: src=0
    hipMemsetAsync(eww,  0, (size_t)EP_ * 4, stream);   // pad entries: w=0
    deg_cnt_k<<<(E_ + 255) / 256, 256, 0, stream>>>(srcI, dstI, ew, deg, cnt);
    dinv_k<<<(N_ + 255) / 256, 256, 0, stream>>>(deg);
    scan_k<<<1, 1024, 0, stream>>>(cnt, offs);
    hist_k<<<(N_ + 255) / 256, 256, 0, stream>>>(cnt, hist);
    hscan_k<<<1, NBIN_, 0, stream>>>(hist, hoff);
    permscatter_k<<<(N_ + 255) / 256, 256, 0, stream>>>(cnt, hoff, hfil, perm);
    hipMemsetAsync(cnt, 0, (size_t)N_ * 4, stream);
    scatter_k<<<(E_ + 255) / 256, 256, 0, stream>>>(srcI, dstI, ew, deg, offs, cnt,
                                                    esrc, eww);

    // bf16 weights
    wprep_k<<<(WTOT_ + 255) / 256, 256, 0, stream>>>(cw, w1, w2, wtc, wt1, wt2);

    // x -> [N,B,C] (fp32 + bf16 image)
    transpose_in_k<<<(N_ * B_ * 16) / 256, 256, 0, stream>>>(x, h_t, hb);

    for (int b = 0; b < NB_; ++b) {
        spmm_ph_k<<<PH_ * NCHK_, 256, 0, stream>>>(hb, t1b, offs, esrc, eww, perm);
        spmm_ph_k<<<PH_ * NCHK_, 256, 0, stream>>>(t1b, sb, offs, esrc, eww, perm);
        mlp_mfma_k<<<NR_ / 64, 256, 0, stream>>>(h_t, hb, t1b, sb,
                                                 wtc + (size_t)b * SZ1_,
                                                 wt1 + (size_t)b * SZ2_,
                                                 wt2 + (size_t)b * SZ3_,
                                                 cb + (size_t)b * DIM_,
                                                 b1 + (size_t)b * DIM_,
                                                 b2 + (size_t)b * C_,
                                                 beta + b);
    }

    // [N,B,C] -> out
    transpose_out_k<<<(N_ * B_ * 16) / 256, 256, 0, stream>>>(h_t, out);
}